// Round 1
// baseline (193.570 us; speedup 1.0000x reference)
//
#include <hip/hip_runtime.h>
#include <math.h>

#define N_ 8
#define C_ 256
#define P_ 784
#define K_ 64
#define NP_ 6272      // N_*P_
#define F_ 16384      // K_*C_
#define FEPS 1e-12f
#define BNEPS 1e-5f

__device__ __forceinline__ float wave_sum(float v) {
#pragma unroll
  for (int s = 1; s < 64; s <<= 1) v += __shfl_xor(v, s, 64);
  return v;
}
__device__ __forceinline__ float wave_max(float v) {
#pragma unroll
  for (int s = 1; s < 64; s <<= 1) v = fmaxf(v, __shfl_xor(v, s, 64));
  return v;
}

// Blocks 0..24: per-position rinv = 1/max(||x_p||,eps), xn2 = ||xn||^2.
// Block 25: cn2[k] = ||centroid_k||^2.
__global__ __launch_bounds__(256) void k_prep(const float* __restrict__ x,
                                              const float* __restrict__ cent,
                                              float* __restrict__ rinv,
                                              float* __restrict__ xn2,
                                              float* __restrict__ cn2) {
  __shared__ float red[4][64];
  int b = blockIdx.x, t = threadIdx.x;
  if (b < 25) {
    int tid = b * 256 + t;
    if (tid < NP_) {
      int n = tid / P_, p = tid % P_;
      const float* base = x + (size_t)n * C_ * P_ + p;
      float ssq = 0.f;
#pragma unroll 8
      for (int c = 0; c < C_; ++c) { float v = base[(size_t)c * P_]; ssq += v * v; }
      float r = 1.0f / fmaxf(sqrtf(ssq), FEPS);
      rinv[tid] = r;
      xn2[tid] = ssq * r * r;
    }
  } else {
    int k = t & 63, part = t >> 6;
    const float* row = cent + (size_t)k * C_ + part * 64;
    float s = 0.f;
#pragma unroll 8
    for (int i = 0; i < 64; ++i) { float v = row[i]; s += v * v; }
    red[part][k] = s;
    __syncthreads();
    if (t < 64) cn2[t] = red[0][t] + red[1][t] + red[2][t] + red[3][t];
  }
}

// G[n,kk,p] = sum_c A[kk,c] * x[n,c,p];  A = [conv_w(64xC); centroids(64xC)]
// tile 64kk x 64p, inner C in chunks of 32. grid (13, 2, 8)
__global__ __launch_bounds__(256) void k_gemm1(const float* __restrict__ x,
                                               const float* __restrict__ convw,
                                               const float* __restrict__ cent,
                                               float* __restrict__ G) {
  __shared__ float As[64][33];
  __shared__ float Xs[32][65];
  int n = blockIdx.z;
  int kk0 = blockIdx.y * 64;
  int p0 = blockIdx.x * 64;
  int t = threadIdx.x;
  int tx = t & 15, ty = t >> 4;
  float acc[4][4] = {};
  const float* xb = x + (size_t)n * C_ * P_;
  for (int c0 = 0; c0 < C_; c0 += 32) {
    {
      int r = t >> 5, cc = t & 31;
#pragma unroll
      for (int i = 0; i < 8; ++i) {
        int row = r + i * 8;
        int kk = kk0 + row;
        const float* Ar = (kk < 64) ? (convw + (size_t)kk * C_) : (cent + (size_t)(kk - 64) * C_);
        As[row][cc] = Ar[c0 + cc];
      }
    }
    {
      int rr = t >> 6, pp = t & 63;
#pragma unroll
      for (int i = 0; i < 8; ++i) {
        int c = rr + i * 4;
        int p = p0 + pp;
        Xs[c][pp] = (p < P_) ? xb[(size_t)(c0 + c) * P_ + p] : 0.f;
      }
    }
    __syncthreads();
#pragma unroll
    for (int cc = 0; cc < 32; ++cc) {
      float a[4], bv[4];
#pragma unroll
      for (int i = 0; i < 4; ++i) a[i] = As[ty * 4 + i][cc];
#pragma unroll
      for (int j = 0; j < 4; ++j) bv[j] = Xs[cc][tx * 4 + j];
#pragma unroll
      for (int i = 0; i < 4; ++i)
#pragma unroll
        for (int j = 0; j < 4; ++j) acc[i][j] += a[i] * bv[j];
    }
    __syncthreads();
  }
  float* Gb = G + ((size_t)n * 128 + kk0) * P_ + p0;
#pragma unroll
  for (int i = 0; i < 4; ++i) {
#pragma unroll
    for (int j = 0; j < 4; ++j) {
      int pl = tx * 4 + j;
      if (p0 + pl < P_) Gb[(size_t)(ty * 4 + i) * P_ + pl] = acc[i][j];
    }
  }
}

// Per position: softmax over K, rn, w2 = a/max(rn,eps)*rinv, S += a/max(rn,eps).
// grid (49, 8); block 256 = 4 waves, each wave does 4 positions.
__global__ __launch_bounds__(256) void k_assign(const float* __restrict__ G,
                                                const float* __restrict__ rinv,
                                                const float* __restrict__ xn2v,
                                                const float* __restrict__ cn2,
                                                float* __restrict__ w2,
                                                float* __restrict__ S) {
  __shared__ float w2_lds[64][17];
  __shared__ float w_lds[64][17];
  int n = blockIdx.y;
  int p0 = blockIdx.x * 16;
  int t = threadIdx.x;
  int wv = t >> 6, lane = t & 63;
  float c2 = cn2[lane];
  const float* Gb = G + (size_t)n * 128 * P_;
  for (int j = 0; j < 4; ++j) {
    int p = p0 + wv * 4 + j;
    float r = rinv[n * P_ + p];
    float lg = Gb[(size_t)lane * P_ + p] * r;
    float dt = Gb[(size_t)(64 + lane) * P_ + p] * r;
    float m = wave_max(lg);
    float e = expf(lg - m);
    float ssum = wave_sum(e);
    float a = e / ssum;
    float x2 = xn2v[n * P_ + p];
    float rn2 = wave_sum(a * a * (x2 - 2.f * dt + c2));
    float wf = 1.0f / fmaxf(sqrtf(rn2), FEPS);
    float wval = a * wf;
    w_lds[lane][wv * 4 + j] = wval;
    w2_lds[lane][wv * 4 + j] = wval * r;
  }
  __syncthreads();
  {
    int pp = t & 15, k4 = t >> 4;
    float* wb = w2 + (size_t)n * K_ * P_ + p0 + pp;
#pragma unroll
    for (int i = 0; i < 4; ++i) {
      int k = k4 + i * 16;
      wb[(size_t)k * P_] = w2_lds[k][pp];
    }
  }
  if (t < 64) {
    float s = 0.f;
#pragma unroll
    for (int pp = 0; pp < 16; ++pp) s += w_lds[t][pp];
    atomicAdd(&S[n * 64 + t], s);
  }
}

// vlad_raw[n,k,c] = sum_p w2[n,k,p]*x[n,c,p]; tile 64k x 64c. grid (4,1,8)
__global__ __launch_bounds__(256) void k_gemm2(const float* __restrict__ x,
                                               const float* __restrict__ w2,
                                               float* __restrict__ vraw) {
  __shared__ float Ws[64][33];
  __shared__ float Xs[64][33];
  int n = blockIdx.z;
  int c0 = blockIdx.x * 64;
  int t = threadIdx.x;
  int tx = t & 15, ty = t >> 4;
  float acc[4][4] = {};
  const float* wb = w2 + (size_t)n * K_ * P_;
  const float* xb = x + (size_t)n * C_ * P_;
  for (int p0 = 0; p0 < P_; p0 += 32) {
    int r = t >> 5, pc = t & 31;
    int p = p0 + pc;
    bool ok = p < P_;
#pragma unroll
    for (int i = 0; i < 8; ++i) {
      int row = r + i * 8;
      Ws[row][pc] = ok ? wb[(size_t)row * P_ + p] : 0.f;
      Xs[row][pc] = ok ? xb[(size_t)(c0 + row) * P_ + p] : 0.f;
    }
    __syncthreads();
#pragma unroll
    for (int pp = 0; pp < 32; ++pp) {
      float a[4], bv[4];
#pragma unroll
      for (int i = 0; i < 4; ++i) a[i] = Ws[ty * 4 + i][pp];
#pragma unroll
      for (int j = 0; j < 4; ++j) bv[j] = Xs[tx * 4 + j][pp];
#pragma unroll
      for (int i = 0; i < 4; ++i)
#pragma unroll
        for (int j = 0; j < 4; ++j) acc[i][j] += a[i] * bv[j];
    }
    __syncthreads();
  }
  float* vb = vraw + (size_t)n * K_ * C_;
#pragma unroll
  for (int i = 0; i < 4; ++i)
#pragma unroll
    for (int j = 0; j < 4; ++j)
      vb[(size_t)(ty * 4 + i) * C_ + c0 + tx * 4 + j] = acc[i][j];
}

// vladn[n,k,c] = (vraw - cent*S) / max(||.||_c, eps). grid 512 (n*64+k)
__global__ __launch_bounds__(256) void k_vladnorm(const float* __restrict__ vraw,
                                                  const float* __restrict__ cent,
                                                  const float* __restrict__ S,
                                                  float* __restrict__ vladn) {
  __shared__ float red[4];
  int b = blockIdx.x;
  int k = b & 63;
  int c = threadIdx.x;
  float val = vraw[(size_t)b * C_ + c] - cent[(size_t)k * C_ + c] * S[b];
  float ss = wave_sum(val * val);
  int wv = threadIdx.x >> 6, lane = threadIdx.x & 63;
  if (lane == 0) red[wv] = ss;
  __syncthreads();
  float tot = red[0] + red[1] + red[2] + red[3];
  float inv = 1.0f / fmaxf(sqrtf(tot), FEPS);
  vladn[(size_t)b * C_ + c] = val * inv;
}

// BatchNorm over n (biased var) + bn affine; accumulate per-n ssq into nrm.
// grid 64; thread = one feature f.
__global__ __launch_bounds__(256) void k_bn(const float* __restrict__ vladn,
                                            const float* __restrict__ bnw,
                                            const float* __restrict__ bnb,
                                            float* __restrict__ ybuf,
                                            float* __restrict__ nrm) {
  int f = blockIdx.x * 256 + threadIdx.x;
  float v[N_];
  float s = 0.f;
#pragma unroll
  for (int n = 0; n < N_; ++n) { v[n] = vladn[(size_t)n * F_ + f]; s += v[n]; }
  float mean = s * (1.0f / N_);
  float s2 = 0.f;
#pragma unroll
  for (int n = 0; n < N_; ++n) { float d = v[n] - mean; s2 += d * d; }
  float var = s2 * (1.0f / N_);
  float sc = bnw[f] / sqrtf(var + BNEPS);
  float bb = bnb[f];
  float y[N_];
#pragma unroll
  for (int n = 0; n < N_; ++n) {
    y[n] = (v[n] - mean) * sc + bb;
    ybuf[(size_t)n * F_ + f] = y[n];
  }
  int lane = threadIdx.x & 63;
#pragma unroll
  for (int n = 0; n < N_; ++n) {
    float q = wave_sum(y[n] * y[n]);
    if (lane == 0) atomicAdd(&nrm[n], q);
  }
}

// out = y / max(||y_n||, eps). grid 512.
__global__ __launch_bounds__(256) void k_final(const float* __restrict__ ybuf,
                                               const float* __restrict__ nrm,
                                               float* __restrict__ out) {
  int idx = blockIdx.x * 256 + threadIdx.x;
  int n = idx >> 14;
  float inv = 1.0f / fmaxf(sqrtf(nrm[n]), FEPS);
  out[idx] = ybuf[idx] * inv;
}

extern "C" void kernel_launch(void* const* d_in, const int* in_sizes, int n_in,
                              void* d_out, int out_size, void* d_ws, size_t ws_size,
                              hipStream_t stream) {
  const float* x = (const float*)d_in[0];
  const float* convw = (const float*)d_in[1];
  const float* cent = (const float*)d_in[2];
  const float* bnw = (const float*)d_in[3];
  const float* bnb = (const float*)d_in[4];
  float* out = (float*)d_out;
  float* ws = (float*)d_ws;

  float* rinv = ws;                 // 6272
  float* xn2 = ws + 6272;           // 6272
  float* cn2 = ws + 12544;          // 64
  float* S = ws + 12608;            // 512
  float* nrm = ws + 13120;          // 8
  float* G = ws + 13184;            // 8*128*784 = 802816
  float* w2 = ws + 816000;          // 8*64*784  = 401408
  float* vraw = ws + 1217408;       // 131072
  float* vladn = ws + 1348480;      // 131072
  float* ybuf = ws + 1479552;       // 131072  (end: 1610624 floats ~6.4MB)

  hipMemsetAsync(S, 0, 520 * sizeof(float), stream);  // S + nrm

  k_prep<<<26, 256, 0, stream>>>(x, cent, rinv, xn2, cn2);
  k_gemm1<<<dim3(13, 2, 8), 256, 0, stream>>>(x, convw, cent, G);
  k_assign<<<dim3(49, 8), 256, 0, stream>>>(G, rinv, xn2, cn2, w2, S);
  k_gemm2<<<dim3(4, 1, 8), 256, 0, stream>>>(x, w2, vraw);
  k_vladnorm<<<512, 256, 0, stream>>>(vraw, cent, S, vladn);
  k_bn<<<64, 256, 0, stream>>>(vladn, bnw, bnb, ybuf, nrm);
  k_final<<<512, 256, 0, stream>>>(ybuf, nrm, out);
}

// Round 2
// 98.475 us; speedup vs baseline: 1.9657x; 1.9657x over previous
//
#include <hip/hip_runtime.h>
#include <math.h>

#define N_ 8
#define C_ 256
#define P_ 784
#define K_ 64
#define NP_ 6272      // N_*P_
#define F_ 16384      // K_*C_
#define FEPS 1e-12f
#define BNEPS 1e-5f

__device__ __forceinline__ float wave_sum(float v) {
#pragma unroll
  for (int s = 1; s < 64; s <<= 1) v += __shfl_xor(v, s, 64);
  return v;
}
__device__ __forceinline__ float wave_max(float v) {
#pragma unroll
  for (int s = 1; s < 64; s <<= 1) v = fmaxf(v, __shfl_xor(v, s, 64));
  return v;
}

// Blocks 0..24: per-position rinv = 1/max(||x_p||,eps), xn2 = ||xn||^2.
// Block 25: cn2[k] = ||centroid_k||^2.
__global__ __launch_bounds__(256) void k_prep(const float* __restrict__ x,
                                              const float* __restrict__ cent,
                                              float* __restrict__ rinv,
                                              float* __restrict__ xn2,
                                              float* __restrict__ cn2) {
  __shared__ float red[4][64];
  int b = blockIdx.x, t = threadIdx.x;
  if (b < 25) {
    int tid = b * 256 + t;
    if (tid < NP_) {
      int n = tid / P_, p = tid % P_;
      const float* base = x + (size_t)n * C_ * P_ + p;
      float ssq = 0.f;
#pragma unroll 8
      for (int c = 0; c < C_; ++c) { float v = base[(size_t)c * P_]; ssq += v * v; }
      float r = 1.0f / fmaxf(sqrtf(ssq), FEPS);
      rinv[tid] = r;
      xn2[tid] = ssq * r * r;
    }
  } else {
    int k = t & 63, part = t >> 6;
    const float* row = cent + (size_t)k * C_ + part * 64;
    float s = 0.f;
#pragma unroll 8
    for (int i = 0; i < 64; ++i) { float v = row[i]; s += v * v; }
    red[part][k] = s;
    __syncthreads();
    if (t < 64) cn2[t] = red[0][t] + red[1][t] + red[2][t] + red[3][t];
  }
}

// Gp[half][n][kk][p] = sum_{c in half} A[kk,c] * x[n,c,p]
// A = [conv_w(64xC); centroids(64xC)]; split C into 2 halves of 128.
// grid (13, 2, 16): z = n*2+half. 416 blocks, 4 c-chunks each.
__global__ __launch_bounds__(256) void k_gemm1(const float* __restrict__ x,
                                               const float* __restrict__ convw,
                                               const float* __restrict__ cent,
                                               float* __restrict__ Gp) {
  __shared__ float AsT[32][68];   // [cc][row], row = kk within tile
  __shared__ float Xs[32][68];    // [cc][pp]
  int z = blockIdx.z;
  int n = z >> 1, half = z & 1;
  int kk0 = blockIdx.y * 64;
  int p0 = blockIdx.x * 64;
  int t = threadIdx.x;
  int tx = t & 15, ty = t >> 4;
  float acc[4][4] = {};
  const float* xb = x + (size_t)n * C_ * P_;
  int cbase = half * 128;
  for (int c0 = cbase; c0 < cbase + 128; c0 += 32) {
    {
      int r = t >> 5, cc = t & 31;
#pragma unroll
      for (int i = 0; i < 8; ++i) {
        int row = r + i * 8;
        int kk = kk0 + row;
        const float* Ar = (kk < 64) ? (convw + (size_t)kk * C_) : (cent + (size_t)(kk - 64) * C_);
        AsT[cc][row] = Ar[c0 + cc];
      }
    }
    {
      int rr = t >> 6, pp = t & 63;
#pragma unroll
      for (int i = 0; i < 8; ++i) {
        int c = rr + i * 4;
        int p = p0 + pp;
        Xs[c][pp] = (p < P_) ? xb[(size_t)(c0 + c) * P_ + p] : 0.f;
      }
    }
    __syncthreads();
#pragma unroll
    for (int cc = 0; cc < 32; ++cc) {
      float4 a = *(const float4*)&AsT[cc][ty * 4];
      float4 bv = *(const float4*)&Xs[cc][tx * 4];
      float av[4] = {a.x, a.y, a.z, a.w};
      float bb[4] = {bv.x, bv.y, bv.z, bv.w};
#pragma unroll
      for (int i = 0; i < 4; ++i)
#pragma unroll
        for (int j = 0; j < 4; ++j) acc[i][j] += av[i] * bb[j];
    }
    __syncthreads();
  }
  float* Gb = Gp + ((size_t)(half * N_ + n) * 128 + kk0) * P_ + p0;
#pragma unroll
  for (int i = 0; i < 4; ++i) {
#pragma unroll
    for (int j = 0; j < 4; ++j) {
      int pl = tx * 4 + j;
      if (p0 + pl < P_) Gb[(size_t)(ty * 4 + i) * P_ + pl] = acc[i][j];
    }
  }
}

// Per position: softmax over K, rn, w2 = a/max(rn,eps)*rinv, S += a/max(rn,eps).
// grid (49, 8); block 256 = 4 waves, each wave does 4 positions.
__global__ __launch_bounds__(256) void k_assign(const float* __restrict__ Gp,
                                                const float* __restrict__ rinv,
                                                const float* __restrict__ xn2v,
                                                const float* __restrict__ cn2,
                                                float* __restrict__ w2,
                                                float* __restrict__ S) {
  __shared__ float w2_lds[64][17];
  __shared__ float w_lds[64][17];
  int n = blockIdx.y;
  int p0 = blockIdx.x * 16;
  int t = threadIdx.x;
  int wv = t >> 6, lane = t & 63;
  float c2 = cn2[lane];
  const float* Gb0 = Gp + (size_t)n * 128 * P_;
  const float* Gb1 = Gp + (size_t)(N_ + n) * 128 * P_;
  for (int j = 0; j < 4; ++j) {
    int p = p0 + wv * 4 + j;
    float r = rinv[n * P_ + p];
    float lg = (Gb0[(size_t)lane * P_ + p] + Gb1[(size_t)lane * P_ + p]) * r;
    float dt = (Gb0[(size_t)(64 + lane) * P_ + p] + Gb1[(size_t)(64 + lane) * P_ + p]) * r;
    float m = wave_max(lg);
    float e = expf(lg - m);
    float ssum = wave_sum(e);
    float a = e / ssum;
    float x2 = xn2v[n * P_ + p];
    float rn2 = wave_sum(a * a * (x2 - 2.f * dt + c2));
    float wf = 1.0f / fmaxf(sqrtf(rn2), FEPS);
    float wval = a * wf;
    w_lds[lane][wv * 4 + j] = wval;
    w2_lds[lane][wv * 4 + j] = wval * r;
  }
  __syncthreads();
  {
    int pp = t & 15, k4 = t >> 4;
    float* wb = w2 + (size_t)n * K_ * P_ + p0 + pp;
#pragma unroll
    for (int i = 0; i < 4; ++i) {
      int k = k4 + i * 16;
      wb[(size_t)k * P_] = w2_lds[k][pp];
    }
  }
  if (t < 64) {
    float s = 0.f;
#pragma unroll
    for (int pp = 0; pp < 16; ++pp) s += w_lds[t][pp];
    atomicAdd(&S[n * 64 + t], s);
  }
}

// vpart[s][n][k][c] = sum_{p in slice s} w2[n,k,p]*x[n,c,p]
// grid (4 c-tiles, 8 splits, 8 n) = 256 blocks, 4 p-chunks each.
__global__ __launch_bounds__(256) void k_gemm2(const float* __restrict__ x,
                                               const float* __restrict__ w2,
                                               float* __restrict__ vpart) {
  __shared__ float WsT[32][68];   // [pp][k]
  __shared__ float XsT[32][68];   // [pp][c]
  int n = blockIdx.z, s = blockIdx.y;
  int c0 = blockIdx.x * 64;
  int t = threadIdx.x;
  int tx = t & 15, ty = t >> 4;
  float acc[4][4] = {};
  const float* wb = w2 + (size_t)n * K_ * P_;
  const float* xb = x + (size_t)n * C_ * P_;
  int pbase = s * 98;
  for (int q = 0; q < 98; q += 32) {
    int r = t >> 5, pc = t & 31;
    bool ok = (q + pc) < 98;
    int p = pbase + q + pc;
#pragma unroll
    for (int i = 0; i < 8; ++i) {
      int row = r + i * 8;
      WsT[pc][row] = ok ? wb[(size_t)row * P_ + p] : 0.f;
      XsT[pc][row] = ok ? xb[(size_t)(c0 + row) * P_ + p] : 0.f;
    }
    __syncthreads();
#pragma unroll
    for (int pp = 0; pp < 32; ++pp) {
      float4 a = *(const float4*)&WsT[pp][ty * 4];
      float4 bv = *(const float4*)&XsT[pp][tx * 4];
      float av[4] = {a.x, a.y, a.z, a.w};
      float bb[4] = {bv.x, bv.y, bv.z, bv.w};
#pragma unroll
      for (int i = 0; i < 4; ++i)
#pragma unroll
        for (int j = 0; j < 4; ++j) acc[i][j] += av[i] * bb[j];
    }
    __syncthreads();
  }
  float* vb = vpart + (size_t)(s * N_ + n) * K_ * C_;
#pragma unroll
  for (int i = 0; i < 4; ++i)
#pragma unroll
    for (int j = 0; j < 4; ++j)
      vb[(size_t)(ty * 4 + i) * C_ + c0 + tx * 4 + j] = acc[i][j];
}

// vladn[n,k,c] = (sum_s vpart - cent*S) / max(||.||_c, eps). grid 512 (b=n*64+k)
__global__ __launch_bounds__(256) void k_vladnorm(const float* __restrict__ vpart,
                                                  const float* __restrict__ cent,
                                                  const float* __restrict__ S,
                                                  float* __restrict__ vladn) {
  __shared__ float red[4];
  int b = blockIdx.x;
  int k = b & 63;
  int c = threadIdx.x;
  float val = 0.f;
#pragma unroll
  for (int s = 0; s < 8; ++s) val += vpart[(size_t)(s * 512 + b) * C_ + c];
  val -= cent[(size_t)k * C_ + c] * S[b];
  float ss = wave_sum(val * val);
  int wv = threadIdx.x >> 6, lane = threadIdx.x & 63;
  if (lane == 0) red[wv] = ss;
  __syncthreads();
  float tot = red[0] + red[1] + red[2] + red[3];
  float inv = 1.0f / fmaxf(sqrtf(tot), FEPS);
  vladn[(size_t)b * C_ + c] = val * inv;
}

// BatchNorm over n (biased var) + bn affine; accumulate per-n ssq into nrm.
// grid 64; thread = one feature f.
__global__ __launch_bounds__(256) void k_bn(const float* __restrict__ vladn,
                                            const float* __restrict__ bnw,
                                            const float* __restrict__ bnb,
                                            float* __restrict__ ybuf,
                                            float* __restrict__ nrm) {
  int f = blockIdx.x * 256 + threadIdx.x;
  float v[N_];
  float s = 0.f;
#pragma unroll
  for (int n = 0; n < N_; ++n) { v[n] = vladn[(size_t)n * F_ + f]; s += v[n]; }
  float mean = s * (1.0f / N_);
  float s2 = 0.f;
#pragma unroll
  for (int n = 0; n < N_; ++n) { float d = v[n] - mean; s2 += d * d; }
  float var = s2 * (1.0f / N_);
  float sc = bnw[f] / sqrtf(var + BNEPS);
  float bb = bnb[f];
  float y[N_];
#pragma unroll
  for (int n = 0; n < N_; ++n) {
    y[n] = (v[n] - mean) * sc + bb;
    ybuf[(size_t)n * F_ + f] = y[n];
  }
  int lane = threadIdx.x & 63;
#pragma unroll
  for (int n = 0; n < N_; ++n) {
    float q = wave_sum(y[n] * y[n]);
    if (lane == 0) atomicAdd(&nrm[n], q);
  }
}

// out = y / max(||y_n||, eps). grid 512.
__global__ __launch_bounds__(256) void k_final(const float* __restrict__ ybuf,
                                               const float* __restrict__ nrm,
                                               float* __restrict__ out) {
  int idx = blockIdx.x * 256 + threadIdx.x;
  int n = idx >> 14;
  float inv = 1.0f / fmaxf(sqrtf(nrm[n]), FEPS);
  out[idx] = ybuf[idx] * inv;
}

extern "C" void kernel_launch(void* const* d_in, const int* in_sizes, int n_in,
                              void* d_out, int out_size, void* d_ws, size_t ws_size,
                              hipStream_t stream) {
  const float* x = (const float*)d_in[0];
  const float* convw = (const float*)d_in[1];
  const float* cent = (const float*)d_in[2];
  const float* bnw = (const float*)d_in[3];
  const float* bnb = (const float*)d_in[4];
  float* out = (float*)d_out;
  float* ws = (float*)d_ws;

  float* rinv = ws;                 // 6272
  float* xn2 = ws + 6272;           // 6272
  float* cn2 = ws + 12544;          // 64
  float* S = ws + 12608;            // 512
  float* nrm = ws + 13120;          // 8
  float* Gp = ws + 13184;           // 2 * 8*128*784 = 1605632
  float* w2 = ws + 1618816;         // 8*64*784 = 401408
  float* vpart = ws + 2020224;      // 8 * 131072 = 1048576
  float* vladn = ws + 3068800;      // 131072
  float* ybuf = ws + 3199872;       // 131072  (end: 3330944 floats ~13.3MB)

  hipMemsetAsync(S, 0, 520 * sizeof(float), stream);  // S + nrm

  k_prep<<<26, 256, 0, stream>>>(x, cent, rinv, xn2, cn2);
  k_gemm1<<<dim3(13, 2, 16), 256, 0, stream>>>(x, convw, cent, Gp);
  k_assign<<<dim3(49, 8), 256, 0, stream>>>(Gp, rinv, xn2, cn2, w2, S);
  k_gemm2<<<dim3(4, 8, 8), 256, 0, stream>>>(x, w2, vpart);
  k_vladnorm<<<512, 256, 0, stream>>>(vpart, cent, S, vladn);
  k_bn<<<64, 256, 0, stream>>>(vladn, bnw, bnb, ybuf, nrm);
  k_final<<<512, 256, 0, stream>>>(ybuf, nrm, out);
}

// Round 3
// 68.264 us; speedup vs baseline: 2.8356x; 1.4426x over previous
//
#include <hip/hip_runtime.h>
#include <math.h>

#define N_ 8
#define C_ 256
#define P_ 784
#define K_ 64
#define NP_ 6272      // N_*P_
#define F_ 16384      // K_*C_
#define FEPS 1e-12f
#define BNEPS 1e-5f

__device__ __forceinline__ float wave_sum(float v) {
#pragma unroll
  for (int s = 1; s < 64; s <<= 1) v += __shfl_xor(v, s, 64);
  return v;
}
__device__ __forceinline__ float wave_max(float v) {
#pragma unroll
  for (int s = 1; s < 64; s <<= 1) v = fmaxf(v, __shfl_xor(v, s, 64));
  return v;
}

// Blocks 0..24: per-position rinv = 1/max(||x_p||,eps), xn2 = ||xn||^2.
// Block 25: cn2[k] = ||centroid_k||^2.
__global__ __launch_bounds__(256) void k_prep(const float* __restrict__ x,
                                              const float* __restrict__ cent,
                                              float* __restrict__ rinv,
                                              float* __restrict__ xn2,
                                              float* __restrict__ cn2) {
  __shared__ float red[4][64];
  int b = blockIdx.x, t = threadIdx.x;
  if (b < 25) {
    int tid = b * 256 + t;
    if (tid < NP_) {
      int n = tid / P_, p = tid % P_;
      const float* base = x + (size_t)n * C_ * P_ + p;
      float ssq = 0.f;
#pragma unroll 8
      for (int c = 0; c < C_; ++c) { float v = base[(size_t)c * P_]; ssq += v * v; }
      float r = 1.0f / fmaxf(sqrtf(ssq), FEPS);
      rinv[tid] = r;
      xn2[tid] = ssq * r * r;
    }
  } else {
    int k = t & 63, part = t >> 6;
    const float* row = cent + (size_t)k * C_ + part * 64;
    float s = 0.f;
#pragma unroll 8
    for (int i = 0; i < 64; ++i) { float v = row[i]; s += v * v; }
    red[part][k] = s;
    __syncthreads();
    if (t < 64) cn2[t] = red[0][t] + red[1][t] + red[2][t] + red[3][t];
  }
}

// Gp[half][n][p][kk] = sum_{c in half} A[kk,c] * x[n,c,p]  (kk-major inner dim = 128)
// A = [conv_w(64xC); centroids(64xC)]; split C into 2 halves of 128.
// grid (13, 2, 16): z = n*2+half. 416 blocks, 4 c-chunks each.
__global__ __launch_bounds__(256) void k_gemm1(const float* __restrict__ x,
                                               const float* __restrict__ convw,
                                               const float* __restrict__ cent,
                                               float* __restrict__ Gp) {
  __shared__ float AsT[32][68];   // [cc][row], row = kk within tile
  __shared__ float Xs[32][68];    // [cc][pp]
  int z = blockIdx.z;
  int n = z >> 1, half = z & 1;
  int kk0 = blockIdx.y * 64;
  int p0 = blockIdx.x * 64;
  int t = threadIdx.x;
  int tx = t & 15, ty = t >> 4;
  float acc[4][4] = {};
  const float* xb = x + (size_t)n * C_ * P_;
  int cbase = half * 128;
  for (int c0 = cbase; c0 < cbase + 128; c0 += 32) {
    {
      int r = t >> 5, cc = t & 31;
#pragma unroll
      for (int i = 0; i < 8; ++i) {
        int row = r + i * 8;
        int kk = kk0 + row;
        const float* Ar = (kk < 64) ? (convw + (size_t)kk * C_) : (cent + (size_t)(kk - 64) * C_);
        AsT[cc][row] = Ar[c0 + cc];
      }
    }
    {
      int rr = t >> 6, pp = t & 63;
#pragma unroll
      for (int i = 0; i < 8; ++i) {
        int c = rr + i * 4;
        int p = p0 + pp;
        Xs[c][pp] = (p < P_) ? xb[(size_t)(c0 + c) * P_ + p] : 0.f;
      }
    }
    __syncthreads();
#pragma unroll
    for (int cc = 0; cc < 32; ++cc) {
      float4 a = *(const float4*)&AsT[cc][ty * 4];
      float4 bv = *(const float4*)&Xs[cc][tx * 4];
      float av[4] = {a.x, a.y, a.z, a.w};
      float bb[4] = {bv.x, bv.y, bv.z, bv.w};
#pragma unroll
      for (int i = 0; i < 4; ++i)
#pragma unroll
        for (int j = 0; j < 4; ++j) acc[i][j] += av[i] * bb[j];
    }
    __syncthreads();
  }
  // store transposed: Gp[((half*8+n)*784 + p)*128 + kk]
  float* Gb = Gp + (size_t)(half * N_ + n) * P_ * 128;
#pragma unroll
  for (int j = 0; j < 4; ++j) {
    int p = p0 + tx * 4 + j;
    if (p < P_) {
      float4 v = make_float4(acc[0][j], acc[1][j], acc[2][j], acc[3][j]);
      *(float4*)&Gb[(size_t)p * 128 + kk0 + ty * 4] = v;
    }
  }
}

// Per position: softmax over K, rn, w2 = a/max(rn,eps)*rinv, Spart = per-block sum.
// grid (49, 8); block 256 = 4 waves, each wave does 4 positions.
__global__ __launch_bounds__(256) void k_assign(const float* __restrict__ Gp,
                                                const float* __restrict__ rinv,
                                                const float* __restrict__ xn2v,
                                                const float* __restrict__ cn2,
                                                float* __restrict__ w2,
                                                float* __restrict__ Spart) {
  __shared__ float w2_lds[64][17];
  __shared__ float w_lds[64][17];
  int n = blockIdx.y;
  int p0 = blockIdx.x * 16;
  int t = threadIdx.x;
  int wv = t >> 6, lane = t & 63;
  float c2 = cn2[lane];
  const float* Gb0 = Gp + (size_t)n * P_ * 128;
  const float* Gb1 = Gp + (size_t)(N_ + n) * P_ * 128;
  for (int j = 0; j < 4; ++j) {
    int p = p0 + wv * 4 + j;
    float r = rinv[n * P_ + p];
    float lg = (Gb0[(size_t)p * 128 + lane] + Gb1[(size_t)p * 128 + lane]) * r;
    float dt = (Gb0[(size_t)p * 128 + 64 + lane] + Gb1[(size_t)p * 128 + 64 + lane]) * r;
    float m = wave_max(lg);
    float e = expf(lg - m);
    float ssum = wave_sum(e);
    float a = e / ssum;
    float x2 = xn2v[n * P_ + p];
    float rn2 = wave_sum(a * a * (x2 - 2.f * dt + c2));
    float wf = 1.0f / fmaxf(sqrtf(rn2), FEPS);
    float wval = a * wf;
    w_lds[lane][wv * 4 + j] = wval;
    w2_lds[lane][wv * 4 + j] = wval * r;
  }
  __syncthreads();
  {
    int pp = t & 15, k4 = t >> 4;
    float* wb = w2 + (size_t)n * K_ * P_ + p0 + pp;
#pragma unroll
    for (int i = 0; i < 4; ++i) {
      int k = k4 + i * 16;
      wb[(size_t)k * P_] = w2_lds[k][pp];
    }
  }
  if (t < 64) {
    float s = 0.f;
#pragma unroll
    for (int pp = 0; pp < 16; ++pp) s += w_lds[t][pp];
    Spart[((size_t)blockIdx.x * N_ + n) * 64 + t] = s;
  }
}

// vpart[s][n][k][c] = sum_{p in slice s} w2[n,k,p]*x[n,c,p]
// grid (4 c-tiles, 8 splits, 8 n) = 256 blocks, 4 p-chunks each.
__global__ __launch_bounds__(256) void k_gemm2(const float* __restrict__ x,
                                               const float* __restrict__ w2,
                                               float* __restrict__ vpart) {
  __shared__ float WsT[32][68];   // [pp][k]
  __shared__ float XsT[32][68];   // [pp][c]
  int n = blockIdx.z, s = blockIdx.y;
  int c0 = blockIdx.x * 64;
  int t = threadIdx.x;
  int tx = t & 15, ty = t >> 4;
  float acc[4][4] = {};
  const float* wb = w2 + (size_t)n * K_ * P_;
  const float* xb = x + (size_t)n * C_ * P_;
  int pbase = s * 98;
  for (int q = 0; q < 98; q += 32) {
    int r = t >> 5, pc = t & 31;
    bool ok = (q + pc) < 98;
    int p = pbase + q + pc;
#pragma unroll
    for (int i = 0; i < 8; ++i) {
      int row = r + i * 8;
      WsT[pc][row] = ok ? wb[(size_t)row * P_ + p] : 0.f;
      XsT[pc][row] = ok ? xb[(size_t)(c0 + row) * P_ + p] : 0.f;
    }
    __syncthreads();
#pragma unroll
    for (int pp = 0; pp < 32; ++pp) {
      float4 a = *(const float4*)&WsT[pp][ty * 4];
      float4 bv = *(const float4*)&XsT[pp][tx * 4];
      float av[4] = {a.x, a.y, a.z, a.w};
      float bb[4] = {bv.x, bv.y, bv.z, bv.w};
#pragma unroll
      for (int i = 0; i < 4; ++i)
#pragma unroll
        for (int j = 0; j < 4; ++j) acc[i][j] += av[i] * bb[j];
    }
    __syncthreads();
  }
  float* vb = vpart + (size_t)(s * N_ + n) * K_ * C_;
#pragma unroll
  for (int i = 0; i < 4; ++i)
#pragma unroll
    for (int j = 0; j < 4; ++j)
      vb[(size_t)(ty * 4 + i) * C_ + c0 + tx * 4 + j] = acc[i][j];
}

// vladn[n,k,c] = (sum_s vpart - cent*sum_s Spart) / max(||.||_c, eps). grid 512 (b=n*64+k)
__global__ __launch_bounds__(256) void k_vladnorm(const float* __restrict__ vpart,
                                                  const float* __restrict__ cent,
                                                  const float* __restrict__ Spart,
                                                  float* __restrict__ vladn) {
  __shared__ float red[4];
  int b = blockIdx.x;
  int n = b >> 6, k = b & 63;
  int c = threadIdx.x;
  float Sb = 0.f;
#pragma unroll
  for (int s = 0; s < 49; ++s) Sb += Spart[((size_t)s * N_ + n) * 64 + k];
  float val = 0.f;
#pragma unroll
  for (int s = 0; s < 8; ++s) val += vpart[(size_t)(s * 512 + b) * C_ + c];
  val -= cent[(size_t)k * C_ + c] * Sb;
  float ss = wave_sum(val * val);
  int wv = threadIdx.x >> 6, lane = threadIdx.x & 63;
  if (lane == 0) red[wv] = ss;
  __syncthreads();
  float tot = red[0] + red[1] + red[2] + red[3];
  float inv = 1.0f / fmaxf(sqrtf(tot), FEPS);
  vladn[(size_t)b * C_ + c] = val * inv;
}

// BatchNorm over n (biased var) + bn affine; per-block partial ssq into nrmpart.
// grid 64; thread = one feature f.
__global__ __launch_bounds__(256) void k_bn(const float* __restrict__ vladn,
                                            const float* __restrict__ bnw,
                                            const float* __restrict__ bnb,
                                            float* __restrict__ ybuf,
                                            float* __restrict__ nrmpart) {
  __shared__ float red[4][8];
  int f = blockIdx.x * 256 + threadIdx.x;
  float v[N_];
  float s = 0.f;
#pragma unroll
  for (int n = 0; n < N_; ++n) { v[n] = vladn[(size_t)n * F_ + f]; s += v[n]; }
  float mean = s * (1.0f / N_);
  float s2 = 0.f;
#pragma unroll
  for (int n = 0; n < N_; ++n) { float d = v[n] - mean; s2 += d * d; }
  float var = s2 * (1.0f / N_);
  float sc = bnw[f] / sqrtf(var + BNEPS);
  float bb = bnb[f];
  float y[N_];
#pragma unroll
  for (int n = 0; n < N_; ++n) {
    y[n] = (v[n] - mean) * sc + bb;
    ybuf[(size_t)n * F_ + f] = y[n];
  }
  int wv = threadIdx.x >> 6, lane = threadIdx.x & 63;
#pragma unroll
  for (int n = 0; n < N_; ++n) {
    float q = wave_sum(y[n] * y[n]);
    if (lane == 0) red[wv][n] = q;
  }
  __syncthreads();
  if (threadIdx.x < N_) {
    int n = threadIdx.x;
    nrmpart[n * 64 + blockIdx.x] = red[0][n] + red[1][n] + red[2][n] + red[3][n];
  }
}

// out = y / max(||y_n||, eps). grid 512.
__global__ __launch_bounds__(256) void k_final(const float* __restrict__ ybuf,
                                               const float* __restrict__ nrmpart,
                                               float* __restrict__ out) {
  int idx = blockIdx.x * 256 + threadIdx.x;
  int n = idx >> 14;
  float tot = 0.f;
#pragma unroll
  for (int b = 0; b < 64; ++b) tot += nrmpart[n * 64 + b];
  float inv = 1.0f / fmaxf(sqrtf(tot), FEPS);
  out[idx] = ybuf[idx] * inv;
}

extern "C" void kernel_launch(void* const* d_in, const int* in_sizes, int n_in,
                              void* d_out, int out_size, void* d_ws, size_t ws_size,
                              hipStream_t stream) {
  const float* x = (const float*)d_in[0];
  const float* convw = (const float*)d_in[1];
  const float* cent = (const float*)d_in[2];
  const float* bnw = (const float*)d_in[3];
  const float* bnb = (const float*)d_in[4];
  float* out = (float*)d_out;
  float* ws = (float*)d_ws;

  float* rinv = ws;                 // 6272
  float* xn2 = ws + 6272;           // 6272
  float* cn2 = ws + 12544;          // 64
  float* Spart = ws + 12608;        // 49*8*64 = 25088
  float* nrmpart = ws + 37696;      // 512
  float* Gp = ws + 38208;           // 2 * 8*784*128 = 1605632
  float* w2 = ws + 1643840;         // 8*64*784 = 401408
  float* vpart = ws + 2045248;      // 8 * 131072 = 1048576
  float* vladn = ws + 3093824;      // 131072
  float* ybuf = ws + 3224896;       // 131072  (end: 3355968 floats ~13.4MB)

  k_prep<<<26, 256, 0, stream>>>(x, cent, rinv, xn2, cn2);
  k_gemm1<<<dim3(13, 2, 16), 256, 0, stream>>>(x, convw, cent, Gp);
  k_assign<<<dim3(49, 8), 256, 0, stream>>>(Gp, rinv, xn2, cn2, w2, Spart);
  k_gemm2<<<dim3(4, 8, 8), 256, 0, stream>>>(x, w2, vpart);
  k_vladnorm<<<512, 256, 0, stream>>>(vpart, cent, Spart, vladn);
  k_bn<<<64, 256, 0, stream>>>(vladn, bnw, bnb, ybuf, nrmpart);
  k_final<<<512, 256, 0, stream>>>(ybuf, nrmpart, out);
}

// Round 4
// 62.128 us; speedup vs baseline: 3.1156x; 1.0987x over previous
//
#include <hip/hip_runtime.h>
#include <math.h>

#define N_ 8
#define C_ 256
#define P_ 784
#define K_ 64
#define F_ 16384      // K_*C_
#define FEPS 1e-12f
#define BNEPS 1e-5f
#define PBLK 25       // ceil(784/32)

__device__ __forceinline__ float wave_sum(float v) {
#pragma unroll
  for (int s = 1; s < 64; s <<= 1) v += __shfl_xor(v, s, 64);
  return v;
}
__device__ __forceinline__ float wave_max(float v) {
#pragma unroll
  for (int s = 1; s < 64; s <<= 1) v = fmaxf(v, __shfl_xor(v, s, 64));
  return v;
}

// Fused: per (n, 32-position tile) block computes
//   G[128][32] = [conv_w;cent] . x  (full C=256),
//   per-p rinv/xn2 (accumulated during staging), cn2 (from cent),
//   softmax over k, rn, w2 = a*wf*r, Spart partial sums.
// grid (25, 8), 256 threads.
__global__ __launch_bounds__(256) void k_fused1(const float* __restrict__ x,
                                                const float* __restrict__ convw,
                                                const float* __restrict__ cent,
                                                float* __restrict__ w2,
                                                float* __restrict__ Spart) {
  __shared__ float As[128][33];     // [kk][cc]
  __shared__ float Xs[32][36];      // [cc][pp]
  __shared__ float G_lds[128][33];  // [kk][pp]
  __shared__ float w2_lds[64][33];  // [k][pp]
  __shared__ float ssq_lds[8][32];
  __shared__ float cn2p[256];
  __shared__ float cn2_lds[64];
  __shared__ float rinv_lds[32];
  __shared__ float xn2_lds[32];
  __shared__ float sp_lds[4][64];

  int pblk = blockIdx.x, n = blockIdx.y;
  int p0 = pblk * 32;
  int t = threadIdx.x;
  int wv = t >> 6, lane = t & 63;
  const float* xb = x + (size_t)n * C_ * P_;

  // cn2 partials: thread t -> k = t>>2, quarter q = t&3 (64 floats each)
  {
    int k = t >> 2, q = t & 3;
    const float* row = cent + (size_t)k * C_ + q * 64;
    float s = 0.f;
#pragma unroll
    for (int i = 0; i < 16; ++i) {
      float4 v = *(const float4*)&row[i * 4];
      s += v.x * v.x + v.y * v.y + v.z * v.z + v.w * v.w;
    }
    cn2p[t] = s;
  }

  int ty = t >> 3, tx = t & 7;   // kk-tile row group (0..31), p group (0..7)
  float acc[4][4] = {};
  float ssq_reg = 0.f;

  for (int ch = 0; ch < 8; ++ch) {
    int c0 = ch * 32;
    // stage A[kk][cc]: thread t: cc = t&31, kk = (t>>5)*16 + i
    {
      int cc = t & 31, kg = t >> 5;
#pragma unroll
      for (int i = 0; i < 16; ++i) {
        int kk = kg * 16 + i;
        const float* Ar = (kk < 64) ? (convw + (size_t)kk * C_) : (cent + (size_t)(kk - 64) * C_);
        As[kk][cc] = Ar[c0 + cc];
      }
    }
    // stage X[cl][pp]: thread t: pp = t&31, cl = (t>>5)*4 + i; accumulate ssq for own pp
    {
      int pp = t & 31, cg = t >> 5;
      int p = p0 + pp;
      bool ok = p < P_;
#pragma unroll
      for (int i = 0; i < 4; ++i) {
        int cl = cg * 4 + i;
        float v = ok ? xb[(size_t)(c0 + cl) * P_ + p] : 0.f;
        Xs[cl][pp] = v;
        ssq_reg += v * v;
      }
    }
    __syncthreads();
    if (ch == 0 && t < 64)  // fold cn2 partials once (read before softmax only)
      cn2_lds[t] = cn2p[t * 4] + cn2p[t * 4 + 1] + cn2p[t * 4 + 2] + cn2p[t * 4 + 3];
#pragma unroll
    for (int cc = 0; cc < 32; ++cc) {
      float4 xv = *(const float4*)&Xs[cc][tx * 4];
      float xa[4] = {xv.x, xv.y, xv.z, xv.w};
#pragma unroll
      for (int i = 0; i < 4; ++i) {
        float a = As[ty * 4 + i][cc];
#pragma unroll
        for (int j = 0; j < 4; ++j) acc[i][j] += a * xa[j];
      }
    }
    __syncthreads();
  }

  // G -> LDS, ssq partials -> LDS
#pragma unroll
  for (int i = 0; i < 4; ++i)
#pragma unroll
    for (int j = 0; j < 4; ++j) G_lds[ty * 4 + i][tx * 4 + j] = acc[i][j];
  ssq_lds[t >> 5][t & 31] = ssq_reg;
  __syncthreads();
  if (t < 32) {
    float s = 0.f;
#pragma unroll
    for (int g = 0; g < 8; ++g) s += ssq_lds[g][t];
    float r = 1.0f / fmaxf(sqrtf(s), FEPS);
    rinv_lds[t] = r;
    xn2_lds[t] = s * r * r;
  }
  __syncthreads();

  // softmax / rn / w2: wave wv handles p_local = wv*8 + jp
  float s_acc = 0.f;
  float c2 = cn2_lds[lane];
  for (int jp = 0; jp < 8; ++jp) {
    int pl = wv * 8 + jp;
    if (p0 + pl >= P_) break;
    float r = rinv_lds[pl];
    float x2 = xn2_lds[pl];
    float lg = G_lds[lane][pl] * r;
    float dt = G_lds[64 + lane][pl] * r;
    float m = wave_max(lg);
    float e = expf(lg - m);
    float ssum = wave_sum(e);
    float a = e / ssum;
    float rn2 = wave_sum(a * a * (x2 - 2.f * dt + c2));
    float wf = 1.0f / fmaxf(sqrtf(rn2), FEPS);
    float wval = a * wf;
    s_acc += wval;
    w2_lds[lane][pl] = wval * r;
  }
  sp_lds[wv][lane] = s_acc;
  __syncthreads();
  if (t < 64) {
    float s = sp_lds[0][t] + sp_lds[1][t] + sp_lds[2][t] + sp_lds[3][t];
    Spart[((size_t)pblk * N_ + n) * 64 + t] = s;
  }
  // w2 global write: thread t: k = (t>>3)+32*it, q = t&7 -> float4 at p0+q*4
  {
    int q = t & 7;
#pragma unroll
    for (int it = 0; it < 2; ++it) {
      int k = (t >> 3) + 32 * it;
      int pidx = q * 4;
      if (p0 + pidx + 3 < P_) {
        float4 v = make_float4(w2_lds[k][pidx], w2_lds[k][pidx + 1],
                               w2_lds[k][pidx + 2], w2_lds[k][pidx + 3]);
        *(float4*)&w2[((size_t)n * K_ + k) * P_ + p0 + pidx] = v;
      }
    }
  }
}

// vpart[s][n][k][c] = sum_{p in slice s} w2[n,k,p]*x[n,c,p]
// grid (4 c-tiles, 8 splits, 8 n) = 256 blocks, 4 p-chunks each.
__global__ __launch_bounds__(256) void k_gemm2(const float* __restrict__ x,
                                               const float* __restrict__ w2,
                                               float* __restrict__ vpart) {
  __shared__ float WsT[32][68];   // [pp][k]
  __shared__ float XsT[32][68];   // [pp][c]
  int n = blockIdx.z, s = blockIdx.y;
  int c0 = blockIdx.x * 64;
  int t = threadIdx.x;
  int tx = t & 15, ty = t >> 4;
  float acc[4][4] = {};
  const float* wb = w2 + (size_t)n * K_ * P_;
  const float* xb = x + (size_t)n * C_ * P_;
  int pbase = s * 98;
  for (int q = 0; q < 98; q += 32) {
    int r = t >> 5, pc = t & 31;
    bool ok = (q + pc) < 98;
    int p = pbase + q + pc;
#pragma unroll
    for (int i = 0; i < 8; ++i) {
      int row = r + i * 8;
      WsT[pc][row] = ok ? wb[(size_t)row * P_ + p] : 0.f;
      XsT[pc][row] = ok ? xb[(size_t)(c0 + row) * P_ + p] : 0.f;
    }
    __syncthreads();
#pragma unroll
    for (int pp = 0; pp < 32; ++pp) {
      float4 a = *(const float4*)&WsT[pp][ty * 4];
      float4 bv = *(const float4*)&XsT[pp][tx * 4];
      float av[4] = {a.x, a.y, a.z, a.w};
      float bb[4] = {bv.x, bv.y, bv.z, bv.w};
#pragma unroll
      for (int i = 0; i < 4; ++i)
#pragma unroll
        for (int j = 0; j < 4; ++j) acc[i][j] += av[i] * bb[j];
    }
    __syncthreads();
  }
  float* vb = vpart + (size_t)(s * N_ + n) * K_ * C_;
#pragma unroll
  for (int i = 0; i < 4; ++i)
#pragma unroll
    for (int j = 0; j < 4; ++j)
      vb[(size_t)(ty * 4 + i) * C_ + c0 + tx * 4 + j] = acc[i][j];
}

// vladn[n,k,c] = (sum_s vpart - cent*sum_s Spart) / max(||.||_c, eps). grid 512 (b=n*64+k)
__global__ __launch_bounds__(256) void k_vladnorm(const float* __restrict__ vpart,
                                                  const float* __restrict__ cent,
                                                  const float* __restrict__ Spart,
                                                  float* __restrict__ vladn) {
  __shared__ float red[4];
  int b = blockIdx.x;
  int n = b >> 6, k = b & 63;
  int c = threadIdx.x;
  float Sb = 0.f;
#pragma unroll
  for (int s = 0; s < PBLK; ++s) Sb += Spart[((size_t)s * N_ + n) * 64 + k];
  float val = 0.f;
#pragma unroll
  for (int s = 0; s < 8; ++s) val += vpart[(size_t)(s * 512 + b) * C_ + c];
  val -= cent[(size_t)k * C_ + c] * Sb;
  float ss = wave_sum(val * val);
  int wv = threadIdx.x >> 6, lane = threadIdx.x & 63;
  if (lane == 0) red[wv] = ss;
  __syncthreads();
  float tot = red[0] + red[1] + red[2] + red[3];
  float inv = 1.0f / fmaxf(sqrtf(tot), FEPS);
  vladn[(size_t)b * C_ + c] = val * inv;
}

// BatchNorm over n (biased var) + bn affine; per-block partial ssq into nrmpart.
// grid 64; thread = one feature f.
__global__ __launch_bounds__(256) void k_bn(const float* __restrict__ vladn,
                                            const float* __restrict__ bnw,
                                            const float* __restrict__ bnb,
                                            float* __restrict__ ybuf,
                                            float* __restrict__ nrmpart) {
  __shared__ float red[4][8];
  int f = blockIdx.x * 256 + threadIdx.x;
  float v[N_];
  float s = 0.f;
#pragma unroll
  for (int n = 0; n < N_; ++n) { v[n] = vladn[(size_t)n * F_ + f]; s += v[n]; }
  float mean = s * (1.0f / N_);
  float s2 = 0.f;
#pragma unroll
  for (int n = 0; n < N_; ++n) { float d = v[n] - mean; s2 += d * d; }
  float var = s2 * (1.0f / N_);
  float sc = bnw[f] / sqrtf(var + BNEPS);
  float bb = bnb[f];
  float y[N_];
#pragma unroll
  for (int n = 0; n < N_; ++n) {
    y[n] = (v[n] - mean) * sc + bb;
    ybuf[(size_t)n * F_ + f] = y[n];
  }
  int wv = threadIdx.x >> 6, lane = threadIdx.x & 63;
#pragma unroll
  for (int n = 0; n < N_; ++n) {
    float q = wave_sum(y[n] * y[n]);
    if (lane == 0) red[wv][n] = q;
  }
  __syncthreads();
  if (threadIdx.x < N_) {
    int n = threadIdx.x;
    nrmpart[n * 64 + blockIdx.x] = red[0][n] + red[1][n] + red[2][n] + red[3][n];
  }
}

// out = y / max(||y_n||, eps). grid 512.
__global__ __launch_bounds__(256) void k_final(const float* __restrict__ ybuf,
                                               const float* __restrict__ nrmpart,
                                               float* __restrict__ out) {
  int idx = blockIdx.x * 256 + threadIdx.x;
  int n = idx >> 14;
  float tot = 0.f;
#pragma unroll
  for (int b = 0; b < 64; ++b) tot += nrmpart[n * 64 + b];
  float inv = 1.0f / fmaxf(sqrtf(tot), FEPS);
  out[idx] = ybuf[idx] * inv;
}

extern "C" void kernel_launch(void* const* d_in, const int* in_sizes, int n_in,
                              void* d_out, int out_size, void* d_ws, size_t ws_size,
                              hipStream_t stream) {
  const float* x = (const float*)d_in[0];
  const float* convw = (const float*)d_in[1];
  const float* cent = (const float*)d_in[2];
  const float* bnw = (const float*)d_in[3];
  const float* bnb = (const float*)d_in[4];
  float* out = (float*)d_out;
  float* ws = (float*)d_ws;

  float* Spart = ws;                // 25*8*64 = 12800
  float* nrmpart = ws + 12800;      // 512
  float* w2 = ws + 13312;           // 8*64*784 = 401408
  float* vpart = ws + 414720;       // 8*512*256 = 1048576
  float* vladn = ws + 1463296;      // 131072
  float* ybuf = ws + 1594368;       // 131072  (end: 1725440 floats ~6.9MB)

  k_fused1<<<dim3(PBLK, N_), 256, 0, stream>>>(x, convw, cent, w2, Spart);
  k_gemm2<<<dim3(4, 8, 8), 256, 0, stream>>>(x, w2, vpart);
  k_vladnorm<<<512, 256, 0, stream>>>(vpart, cent, Spart, vladn);
  k_bn<<<64, 256, 0, stream>>>(vladn, bnw, bnb, ybuf, nrmpart);
  k_final<<<512, 256, 0, stream>>>(ybuf, nrmpart, out);
}

// Round 5
// 57.407 us; speedup vs baseline: 3.3719x; 1.0822x over previous
//
#include <hip/hip_runtime.h>
#include <math.h>

#define N_ 8
#define C_ 256
#define P_ 784
#define K_ 64
#define F_ 16384      // K_*C_
#define FEPS 1e-12f
#define BNEPS 1e-5f
#define PBLK 25       // ceil(784/32)

__device__ __forceinline__ float wave_sum(float v) {
#pragma unroll
  for (int s = 1; s < 64; s <<= 1) v += __shfl_xor(v, s, 64);
  return v;
}
__device__ __forceinline__ float wave_max(float v) {
#pragma unroll
  for (int s = 1; s < 64; s <<= 1) v = fmaxf(v, __shfl_xor(v, s, 64));
  return v;
}

// Fused: per (n, 32-position tile): G[128][32] over full C=256 (8 chunks),
// per-p rinv/xn2 (accumulated during X staging), cn2, softmax, rn, w2, Spart.
// grid (25, 8), 512 threads (8 waves -> >=2 waves/SIMD).
__global__ __launch_bounds__(512) void k_fused1(const float* __restrict__ x,
                                                const float* __restrict__ convw,
                                                const float* __restrict__ cent,
                                                float* __restrict__ w2,
                                                float* __restrict__ Spart) {
  __shared__ float As[128][33];     // [kk][cc]
  __shared__ float Xs[32][34];      // [cc][pp]
  __shared__ float G_lds[128][33];  // [kk][pp]
  __shared__ float w2_lds[64][36];  // [k][pp] (36: float4-aligned rows)
  __shared__ float cn2p[64][9];
  __shared__ float cn2_lds[64];
  __shared__ float ssq_lds[16][33];
  __shared__ float rinv_lds[32];
  __shared__ float xn2_lds[32];
  __shared__ float sp_lds[8][65];

  int pblk = blockIdx.x, n = blockIdx.y;
  int p0 = pblk * 32;
  int t = threadIdx.x;
  int wv = t >> 6, lane = t & 63;
  const float* xb = x + (size_t)n * C_ * P_;

  // cn2 partials: thread t -> k = t>>3, octant = t&7 (32 floats each)
  {
    int k = t >> 3, oct = t & 7;
    const float* row = cent + (size_t)k * C_ + oct * 32;
    float s = 0.f;
#pragma unroll
    for (int i = 0; i < 8; ++i) {
      float4 v = *(const float4*)&row[i * 4];
      s += v.x * v.x + v.y * v.y + v.z * v.z + v.w * v.w;
    }
    cn2p[k][oct] = s;
  }

  int tx = t & 15, ty = t >> 4;   // p-pair id (0..15), kk-quad id (0..31)
  int spp = t & 31, scg = t >> 5; // X staging: position, c-group (0..15)
  float acc[4][2] = {};
  float ssq_reg = 0.f;

  for (int ch = 0; ch < 8; ++ch) {
    int c0 = ch * 32;
    // stage A[kk][cc]: thread: cc = t&31, kg = t>>5 -> rows kg*8..kg*8+7
    {
      int cc = t & 31, kg = t >> 5;
#pragma unroll
      for (int i = 0; i < 8; ++i) {
        int kk = kg * 8 + i;
        const float* Ar = (kk < 64) ? (convw + (size_t)kk * C_) : (cent + (size_t)(kk - 64) * C_);
        As[kk][cc] = Ar[c0 + cc];
      }
    }
    // stage X[cl][pp], accumulate ssq for own (cg,pp) slice
    {
      int p = p0 + spp;
      bool ok = p < P_;
#pragma unroll
      for (int i = 0; i < 2; ++i) {
        int cl = scg * 2 + i;
        float v = ok ? xb[(size_t)(c0 + cl) * P_ + p] : 0.f;
        Xs[cl][spp] = v;
        ssq_reg += v * v;
      }
    }
    __syncthreads();
    if (ch == 0 && t < 64) {
      float s = 0.f;
#pragma unroll
      for (int i = 0; i < 8; ++i) s += cn2p[t][i];
      cn2_lds[t] = s;
    }
#pragma unroll
    for (int cc = 0; cc < 32; ++cc) {
      float2 xv = *(const float2*)&Xs[cc][tx * 2];
      float a0 = As[ty * 4 + 0][cc];
      float a1 = As[ty * 4 + 1][cc];
      float a2 = As[ty * 4 + 2][cc];
      float a3 = As[ty * 4 + 3][cc];
      acc[0][0] += a0 * xv.x; acc[0][1] += a0 * xv.y;
      acc[1][0] += a1 * xv.x; acc[1][1] += a1 * xv.y;
      acc[2][0] += a2 * xv.x; acc[2][1] += a2 * xv.y;
      acc[3][0] += a3 * xv.x; acc[3][1] += a3 * xv.y;
    }
    __syncthreads();
  }

  // G -> LDS, ssq partials -> LDS
#pragma unroll
  for (int i = 0; i < 4; ++i) {
    G_lds[ty * 4 + i][tx * 2 + 0] = acc[i][0];
    G_lds[ty * 4 + i][tx * 2 + 1] = acc[i][1];
  }
  ssq_lds[scg][spp] = ssq_reg;
  __syncthreads();
  if (t < 32) {
    float s = 0.f;
#pragma unroll
    for (int g = 0; g < 16; ++g) s += ssq_lds[g][t];
    float r = 1.0f / fmaxf(sqrtf(s), FEPS);
    rinv_lds[t] = r;
    xn2_lds[t] = s * r * r;
  }
  __syncthreads();

  // softmax / rn / w2: wave wv handles pl = wv*4 + j
  float s_acc = 0.f;
  float c2 = cn2_lds[lane];
#pragma unroll
  for (int j = 0; j < 4; ++j) {
    int pl = wv * 4 + j;
    if (p0 + pl < P_) {   // wave-uniform condition
      float r = rinv_lds[pl];
      float x2 = xn2_lds[pl];
      float lg = G_lds[lane][pl] * r;
      float dt = G_lds[64 + lane][pl] * r;
      float m = wave_max(lg);
      float e = expf(lg - m);
      float ssum = wave_sum(e);
      float a = e / ssum;
      float rn2 = wave_sum(a * a * (x2 - 2.f * dt + c2));
      float wf = 1.0f / fmaxf(sqrtf(rn2), FEPS);
      float wval = a * wf;
      s_acc += wval;
      w2_lds[lane][pl] = wval * r;
    }
  }
  sp_lds[wv][lane] = s_acc;
  __syncthreads();
  if (t < 64) {
    float s = 0.f;
#pragma unroll
    for (int g = 0; g < 8; ++g) s += sp_lds[g][t];
    Spart[((size_t)pblk * N_ + n) * 64 + t] = s;
  }
  // w2 global write: thread t: k = t>>3, q = t&7 -> float4 at p0+q*4
  {
    int k = t >> 3, q = t & 7;
    int p = p0 + q * 4;
    if (p + 3 < P_) {
      float4 v = *(const float4*)&w2_lds[k][q * 4];
      *(float4*)&w2[((size_t)n * K_ + k) * P_ + p] = v;
    }
  }
}

// vpart[s][n][k][c] = sum_{p in slice s} w2[n,k,p]*x[n,c,p]
// grid (4 c-tiles, 8 splits, 8 n) = 256 blocks, 4 p-chunks each.
__global__ __launch_bounds__(256) void k_gemm2(const float* __restrict__ x,
                                               const float* __restrict__ w2,
                                               float* __restrict__ vpart) {
  __shared__ float WsT[32][68];   // [pp][k]
  __shared__ float XsT[32][68];   // [pp][c]
  int n = blockIdx.z, s = blockIdx.y;
  int c0 = blockIdx.x * 64;
  int t = threadIdx.x;
  int tx = t & 15, ty = t >> 4;
  float acc[4][4] = {};
  const float* wb = w2 + (size_t)n * K_ * P_;
  const float* xb = x + (size_t)n * C_ * P_;
  int pbase = s * 98;
  for (int q = 0; q < 98; q += 32) {
    int r = t >> 5, pc = t & 31;
    bool ok = (q + pc) < 98;
    int p = pbase + q + pc;
#pragma unroll
    for (int i = 0; i < 8; ++i) {
      int row = r + i * 8;
      WsT[pc][row] = ok ? wb[(size_t)row * P_ + p] : 0.f;
      XsT[pc][row] = ok ? xb[(size_t)(c0 + row) * P_ + p] : 0.f;
    }
    __syncthreads();
#pragma unroll
    for (int pp = 0; pp < 32; ++pp) {
      float4 a = *(const float4*)&WsT[pp][ty * 4];
      float4 bv = *(const float4*)&XsT[pp][tx * 4];
      float av[4] = {a.x, a.y, a.z, a.w};
      float bb[4] = {bv.x, bv.y, bv.z, bv.w};
#pragma unroll
      for (int i = 0; i < 4; ++i)
#pragma unroll
        for (int j = 0; j < 4; ++j) acc[i][j] += av[i] * bb[j];
    }
    __syncthreads();
  }
  float* vb = vpart + (size_t)(s * N_ + n) * K_ * C_;
#pragma unroll
  for (int i = 0; i < 4; ++i)
#pragma unroll
    for (int j = 0; j < 4; ++j)
      vb[(size_t)(ty * 4 + i) * C_ + c0 + tx * 4 + j] = acc[i][j];
}

// vladn[n,k,c] = (sum_s vpart - cent*sum_s Spart) / max(||.||_c, eps). grid 512 (b=n*64+k)
__global__ __launch_bounds__(256) void k_vladnorm(const float* __restrict__ vpart,
                                                  const float* __restrict__ cent,
                                                  const float* __restrict__ Spart,
                                                  float* __restrict__ vladn) {
  __shared__ float red[4];
  int b = blockIdx.x;
  int n = b >> 6, k = b & 63;
  int c = threadIdx.x;
  float Sb = 0.f;
#pragma unroll
  for (int s = 0; s < PBLK; ++s) Sb += Spart[((size_t)s * N_ + n) * 64 + k];
  float val = 0.f;
#pragma unroll
  for (int s = 0; s < 8; ++s) val += vpart[(size_t)(s * 512 + b) * C_ + c];
  val -= cent[(size_t)k * C_ + c] * Sb;
  float ss = wave_sum(val * val);
  int wv = threadIdx.x >> 6, lane = threadIdx.x & 63;
  if (lane == 0) red[wv] = ss;
  __syncthreads();
  float tot = red[0] + red[1] + red[2] + red[3];
  float inv = 1.0f / fmaxf(sqrtf(tot), FEPS);
  vladn[(size_t)b * C_ + c] = val * inv;
}

// BatchNorm over n (biased var) + bn affine; per-block partial ssq into nrmpart.
__global__ __launch_bounds__(256) void k_bn(const float* __restrict__ vladn,
                                            const float* __restrict__ bnw,
                                            const float* __restrict__ bnb,
                                            float* __restrict__ ybuf,
                                            float* __restrict__ nrmpart) {
  __shared__ float red[4][8];
  int f = blockIdx.x * 256 + threadIdx.x;
  float v[N_];
  float s = 0.f;
#pragma unroll
  for (int n = 0; n < N_; ++n) { v[n] = vladn[(size_t)n * F_ + f]; s += v[n]; }
  float mean = s * (1.0f / N_);
  float s2 = 0.f;
#pragma unroll
  for (int n = 0; n < N_; ++n) { float d = v[n] - mean; s2 += d * d; }
  float var = s2 * (1.0f / N_);
  float sc = bnw[f] / sqrtf(var + BNEPS);
  float bb = bnb[f];
  float y[N_];
#pragma unroll
  for (int n = 0; n < N_; ++n) {
    y[n] = (v[n] - mean) * sc + bb;
    ybuf[(size_t)n * F_ + f] = y[n];
  }
  int wv = threadIdx.x >> 6, lane = threadIdx.x & 63;
#pragma unroll
  for (int n = 0; n < N_; ++n) {
    float q = wave_sum(y[n] * y[n]);
    if (lane == 0) red[wv][n] = q;
  }
  __syncthreads();
  if (threadIdx.x < N_) {
    int n = threadIdx.x;
    nrmpart[n * 64 + blockIdx.x] = red[0][n] + red[1][n] + red[2][n] + red[3][n];
  }
}

// out = y / max(||y_n||, eps). grid 512.
__global__ __launch_bounds__(256) void k_final(const float* __restrict__ ybuf,
                                               const float* __restrict__ nrmpart,
                                               float* __restrict__ out) {
  int idx = blockIdx.x * 256 + threadIdx.x;
  int n = idx >> 14;
  float tot = 0.f;
#pragma unroll
  for (int b = 0; b < 64; ++b) tot += nrmpart[n * 64 + b];
  float inv = 1.0f / fmaxf(sqrtf(tot), FEPS);
  out[idx] = ybuf[idx] * inv;
}

extern "C" void kernel_launch(void* const* d_in, const int* in_sizes, int n_in,
                              void* d_out, int out_size, void* d_ws, size_t ws_size,
                              hipStream_t stream) {
  const float* x = (const float*)d_in[0];
  const float* convw = (const float*)d_in[1];
  const float* cent = (const float*)d_in[2];
  const float* bnw = (const float*)d_in[3];
  const float* bnb = (const float*)d_in[4];
  float* out = (float*)d_out;
  float* ws = (float*)d_ws;

  float* Spart = ws;                // 25*8*64 = 12800
  float* nrmpart = ws + 12800;      // 512
  float* w2 = ws + 13312;           // 8*64*784 = 401408
  float* vpart = ws + 414720;       // 8*512*256 = 1048576
  float* vladn = ws + 1463296;      // 131072
  float* ybuf = ws + 1594368;       // 131072  (end: 1725440 floats ~6.9MB)

  k_fused1<<<dim3(PBLK, N_), 512, 0, stream>>>(x, convw, cent, w2, Spart);
  k_gemm2<<<dim3(4, 8, 8), 256, 0, stream>>>(x, w2, vpart);
  k_vladnorm<<<512, 256, 0, stream>>>(vpart, cent, Spart, vladn);
  k_bn<<<64, 256, 0, stream>>>(vladn, bnw, bnb, ybuf, nrmpart);
  k_final<<<512, 256, 0, stream>>>(ybuf, nrmpart, out);
}